// Round 10
// baseline (892.854 us; speedup 1.0000x reference)
//
#include <hip/hip_runtime.h>

#define N_NODES 100000
#define N_EDGES 1000000
#define HID 64
#define SCAN_B 1024
#define SCAN_NB ((N_NODES + SCAN_B - 1) / SCAN_B)   // 98
#define GATHER_BLOCKS ((N_NODES * 16) / 256)        // 6250
#define HIST_BLOCKS ((N_EDGES + 255) / 256)         // 3907

typedef __attribute__((ext_vector_type(8))) short short8;   // 8 bf16 (4 VGPR)
typedef __attribute__((ext_vector_type(4))) float f32x4;

// f32 -> bf16 bits, round-to-nearest-even
__device__ __forceinline__ unsigned short f2bf(float f) {
    unsigned u = __float_as_uint(f);
    u += 0x7fffu + ((u >> 16) & 1u);
    return (unsigned short)(u >> 16);
}
__device__ __forceinline__ float bf2f(unsigned short u) {
    return __uint_as_float((unsigned)u << 16);
}
__device__ __forceinline__ short8 pack8(float4 a, float4 b) {
    short8 r;
    r[0] = (short)f2bf(a.x); r[1] = (short)f2bf(a.y);
    r[2] = (short)f2bf(a.z); r[3] = (short)f2bf(a.w);
    r[4] = (short)f2bf(b.x); r[5] = (short)f2bf(b.y);
    r[6] = (short)f2bf(b.z); r[7] = (short)f2bf(b.w);
    return r;
}
// 8 consecutive k-elements of weight row `row` starting at k0 (f32 -> bf16)
__device__ __forceinline__ short8 ldw(const float* __restrict__ W, int row, int k0) {
    const float4* p = (const float4*)(W + (size_t)row * HID + k0);
    return pack8(p[0], p[1]);
}

// Fused: x[n] = node_emb[z[n]] (16 thr/node, float4)  +  degree histogram.
__global__ __launch_bounds__(256) void prep_kernel(
    const float* __restrict__ node_emb, const int* __restrict__ z,
    float* __restrict__ x, const int* __restrict__ dst, int* __restrict__ offs)
{
    if (blockIdx.x < GATHER_BLOCKS) {
        int t = blockIdx.x * 256 + threadIdx.x;
        int n = t >> 4, c = t & 15;
        if (n >= N_NODES) return;
        int zi = z[n];
        float4 v = ((const float4*)(node_emb + (size_t)zi * HID))[c];
        ((float4*)(x + (size_t)n * HID))[c] = v;
    } else {
        int e = (blockIdx.x - GATHER_BLOCKS) * 256 + threadIdx.x;
        if (e < N_EDGES) atomicAdd(&offs[dst[e]], 1);
    }
}

// ---- multi-block exclusive scan (3 phases) ----
__global__ __launch_bounds__(1024) void scan1_kernel(
    int* __restrict__ offs, int* __restrict__ bsum)
{
    __shared__ int wsum[16];
    int tid = threadIdx.x, lane = tid & 63, wid = tid >> 6;
    int i = blockIdx.x * SCAN_B + tid;
    int v = (i < N_NODES) ? offs[i] : 0;
    int s = v;
#pragma unroll
    for (int d = 1; d < 64; d <<= 1) {
        int t = __shfl_up(s, (unsigned)d, 64);
        if (lane >= d) s += t;
    }
    if (lane == 63) wsum[wid] = s;
    __syncthreads();
    if (wid == 0) {
        int w = (lane < 16) ? wsum[lane] : 0;
#pragma unroll
        for (int d = 1; d < 16; d <<= 1) {
            int t = __shfl_up(w, (unsigned)d, 64);
            if (lane >= d) w += t;
        }
        if (lane < 16) wsum[lane] = w;
    }
    __syncthreads();
    int woff = (wid == 0) ? 0 : wsum[wid - 1];
    if (i < N_NODES) offs[i] = woff + s - v;     // block-local exclusive
    if (tid == 1023) bsum[blockIdx.x] = wsum[15]; // block total
}

__global__ __launch_bounds__(128) void scan2_kernel(int* __restrict__ bsum)
{
    __shared__ int ws[2];
    int tid = threadIdx.x, lane = tid & 63, wid = tid >> 6;
    int v = (tid < SCAN_NB) ? bsum[tid] : 0;
    int s = v;
#pragma unroll
    for (int d = 1; d < 64; d <<= 1) {
        int t = __shfl_up(s, (unsigned)d, 64);
        if (lane >= d) s += t;
    }
    if (lane == 63) ws[wid] = s;
    __syncthreads();
    int add = (wid == 1) ? ws[0] : 0;
    if (tid < SCAN_NB) bsum[tid] = add + s - v;  // exclusive
}

__global__ __launch_bounds__(1024) void scan3_kernel(
    int* __restrict__ offs, const int* __restrict__ bsum)
{
    int i = blockIdx.x * SCAN_B + threadIdx.x;
    if (i < N_NODES) {
        int v = offs[i] + bsum[blockIdx.x];
        atomicExch(&offs[i], v);   // publish at coherent point for fill's RMW
    }
}

// eid2[slot] = (e, src[e]); offs becomes END offsets after this.
__global__ __launch_bounds__(256) void fill_kernel(
    const int* __restrict__ src, const int* __restrict__ dst,
    int* __restrict__ offs, int2* __restrict__ eid2)
{
    int e = blockIdx.x * 256 + threadIdx.x;
    if (e < N_EDGES) {
        int d = dst[e];
        int pos = atomicAdd(&offs[d], 1);
        eid2[pos] = make_int2(e, src[e]);
    }
}

// Canonicalize slot ranges to ascending edge-id order (launch-invariant sums).
__global__ __launch_bounds__(256) void sort_kernel(
    const int* __restrict__ offs, int2* __restrict__ eid2)
{
    int gt = blockIdx.x * 256 + threadIdx.x;
    int n = gt >> 6;
    int lane = threadIdx.x & 63;
    if (n >= N_NODES) return;                 // wave-uniform
    int start = (n == 0) ? 0 : offs[n - 1];
    int end = offs[n];
    int deg = end - start;
    if (deg <= 1 || deg > 64) return;         // wave-uniform
    int ke = 0x7fffffff, vs = 0;
    if (lane < deg) { int2 t = eid2[start + lane]; ke = t.x; vs = t.y; }
#pragma unroll
    for (int k = 2; k <= 64; k <<= 1) {
        for (int j = k >> 1; j > 0; j >>= 1) {
            int partner = lane ^ j;
            int ke2 = __shfl(ke, partner, 64);
            int vs2 = __shfl(vs, partner, 64);
            bool up = ((lane & k) == 0);
            bool takemin = ((lane < partner) == up);
            bool sw = takemin ? (ke2 < ke) : (ke2 > ke);
            if (sw) { ke = ke2; vs = vs2; }
        }
    }
    if (lane < deg) eid2[start + lane] = make_int2(ke, vs);
}

// ===================== fused conv: agg (phase A) + MFMA MLP (phase B) ====
// Wave owns 16 nodes (100000 = 6250 waves exactly). Phase A: wave-per-node
// aggregation (4 edges in flight, reg-hoisted indices, uniform trip count —
// round-8 exec-mask discipline); the per-node result in = agg + x_in is
// packed bf16 straight into the MFMA A-layout LDS buffer. Phase B: the
// round-9 MFMA MLP body (bit-identical arithmetic).
// FIRST=1 (conv 0): reads f32 ea via eid2, and side-writes the conv-
// invariant slot-ordered bf16 cache eabs[slot][64] + srcs[slot].
// FIRST=0 (convs 1,2): streams eabs SEQUENTIALLY (128 MB vs 256 MB random)
// + srcs; no eid2. x ping-pongs (x_out != x_in) since blocks write nodes
// while others still aggregate.
template<int FIRST>
__global__ __launch_bounds__(256) void conv_kernel(
    const float* __restrict__ x_in, float* __restrict__ x_out,
    const float* __restrict__ ea, unsigned short* __restrict__ eabs,
    int* __restrict__ srcs, const int2* __restrict__ eid2,
    const int* __restrict__ offs,
    const float* __restrict__ W1, const float* __restrict__ b1,
    const float* __restrict__ W2, const float* __restrict__ b2,
    int last_relu)
{
    __shared__ unsigned short hl[4][16][64];   // [wave][node][hid] bf16, 8 KB
    int tid = threadIdx.x;
    int wid = tid >> 6, lane = tid & 63;
    int g = lane >> 4, c = lane & 15;
    int m0 = (blockIdx.x * 4 + wid) * 16;      // first node of this wave
    if (m0 >= N_NODES) return;                 // wave-uniform

    // ---- Phase A: aggregate 16 nodes ----
    int start = (m0 == 0) ? 0 : offs[m0 - 1];
    for (int i = 0; i < 16; ++i) {
        int n = m0 + i;                        // wave-uniform
        int end = offs[n];
        int deg = end - start;
        float4 acc = make_float4(0.f, 0.f, 0.f, 0.f);
        int dmax = deg < 64 ? deg : 64;
        int iters = (dmax + 3) >> 2;           // wave-uniform trip count
        if (FIRST) {
            int2 my = make_int2(0, 0);
            if (lane < deg) my = eid2[start + lane];
            for (int j = 0; j < iters; ++j) {
                int k = g + 4 * j;
                int eidx = __shfl(my.x, k, 64);   // all lanes active
                int sidx = __shfl(my.y, k, 64);
                if (k < dmax) {
                    float4 e4 = ((const float4*)(ea + (size_t)eidx * HID))[c];
                    ushort4 q;
                    q.x = f2bf(e4.x); q.y = f2bf(e4.y);
                    q.z = f2bf(e4.z); q.w = f2bf(e4.w);
                    *(ushort4*)&eabs[(size_t)(start + k) * HID + c * 4] = q;
                    if (c == 0) srcs[start + k] = sidx;
                    float4 x4 = ((const float4*)(x_in + (size_t)sidx * HID))[c];
                    acc.x += fmaxf(x4.x + e4.x, 0.f);
                    acc.y += fmaxf(x4.y + e4.y, 0.f);
                    acc.z += fmaxf(x4.z + e4.z, 0.f);
                    acc.w += fmaxf(x4.w + e4.w, 0.f);
                }
            }
            for (int t = start + 64 + g; t < end; t += 4) {  // deg>64: ~never
                int2 p = eid2[t];
                float4 e4 = ((const float4*)(ea + (size_t)p.x * HID))[c];
                ushort4 q;
                q.x = f2bf(e4.x); q.y = f2bf(e4.y);
                q.z = f2bf(e4.z); q.w = f2bf(e4.w);
                *(ushort4*)&eabs[(size_t)t * HID + c * 4] = q;
                if (c == 0) srcs[t] = p.y;
                float4 x4 = ((const float4*)(x_in + (size_t)p.y * HID))[c];
                acc.x += fmaxf(x4.x + e4.x, 0.f);
                acc.y += fmaxf(x4.y + e4.y, 0.f);
                acc.z += fmaxf(x4.z + e4.z, 0.f);
                acc.w += fmaxf(x4.w + e4.w, 0.f);
            }
        } else {
            int mys = 0;
            if (lane < deg) mys = srcs[start + lane];
            for (int j = 0; j < iters; ++j) {
                int k = g + 4 * j;
                int sidx = __shfl(mys, k, 64);    // all lanes active
                if (k < dmax) {
                    ushort4 q = *(const ushort4*)&eabs[(size_t)(start + k) * HID + c * 4];
                    float4 x4 = ((const float4*)(x_in + (size_t)sidx * HID))[c];
                    acc.x += fmaxf(x4.x + bf2f(q.x), 0.f);
                    acc.y += fmaxf(x4.y + bf2f(q.y), 0.f);
                    acc.z += fmaxf(x4.z + bf2f(q.z), 0.f);
                    acc.w += fmaxf(x4.w + bf2f(q.w), 0.f);
                }
            }
            for (int t = start + 64 + g; t < end; t += 4) {  // deg>64: ~never
                int sidx = srcs[t];
                ushort4 q = *(const ushort4*)&eabs[(size_t)t * HID + c * 4];
                float4 x4 = ((const float4*)(x_in + (size_t)sidx * HID))[c];
                acc.x += fmaxf(x4.x + bf2f(q.x), 0.f);
                acc.y += fmaxf(x4.y + bf2f(q.y), 0.f);
                acc.z += fmaxf(x4.z + bf2f(q.z), 0.f);
                acc.w += fmaxf(x4.w + bf2f(q.w), 0.f);
            }
        }
        // reduce over the 4 edge groups
        acc.x += __shfl_xor(acc.x, 16, 64);
        acc.y += __shfl_xor(acc.y, 16, 64);
        acc.z += __shfl_xor(acc.z, 16, 64);
        acc.w += __shfl_xor(acc.w, 16, 64);
        acc.x += __shfl_xor(acc.x, 32, 64);
        acc.y += __shfl_xor(acc.y, 32, 64);
        acc.z += __shfl_xor(acc.z, 32, 64);
        acc.w += __shfl_xor(acc.w, 32, 64);
        if (g == 0) {                          // in = agg + x_in -> bf16 LDS
            float4 xv = ((const float4*)(x_in + (size_t)n * HID))[c];
            ushort4 q;
            q.x = f2bf(acc.x + xv.x); q.y = f2bf(acc.y + xv.y);
            q.z = f2bf(acc.z + xv.z); q.w = f2bf(acc.w + xv.w);
            *(ushort4*)&hl[wid][i][c * 4] = q;
        }
        start = end;
    }

    // ---- Phase B: MFMA MLP (round-9 body; wave-private LDS, no barrier) --
    short8 af0 = *(const short8*)&hl[wid][c][g * 8];
    short8 af1 = *(const short8*)&hl[wid][c][32 + g * 8];

    f32x4 a10 = {0.f, 0.f, 0.f, 0.f}, a11 = a10, a12 = a10, a13 = a10;
#define L1(JT, ACC) { \
    short8 w0 = ldw(W1, (JT)*16 + c, g * 8); \
    short8 w1 = ldw(W1, (JT)*16 + c, 32 + g * 8); \
    ACC = __builtin_amdgcn_mfma_f32_16x16x32_bf16(af0, w0, ACC, 0, 0, 0); \
    ACC = __builtin_amdgcn_mfma_f32_16x16x32_bf16(af1, w1, ACC, 0, 0, 0); }
    L1(0, a10) L1(1, a11) L1(2, a12) L1(3, a13)
#undef L1

#define HST(JT, ACC) { float bb = b1[(JT) * 16 + c]; \
    hl[wid][4*g + 0][(JT)*16 + c] = f2bf(fmaxf(ACC[0] + bb, 0.f)); \
    hl[wid][4*g + 1][(JT)*16 + c] = f2bf(fmaxf(ACC[1] + bb, 0.f)); \
    hl[wid][4*g + 2][(JT)*16 + c] = f2bf(fmaxf(ACC[2] + bb, 0.f)); \
    hl[wid][4*g + 3][(JT)*16 + c] = f2bf(fmaxf(ACC[3] + bb, 0.f)); }
    HST(0, a10) HST(1, a11) HST(2, a12) HST(3, a13)
#undef HST

    short8 hf0 = *(const short8*)&hl[wid][c][g * 8];
    short8 hf1 = *(const short8*)&hl[wid][c][32 + g * 8];

    f32x4 a20 = {0.f, 0.f, 0.f, 0.f}, a21 = a20, a22 = a20, a23 = a20;
#define L2(CT, ACC) { \
    short8 w0 = ldw(W2, (CT)*16 + c, g * 8); \
    short8 w1 = ldw(W2, (CT)*16 + c, 32 + g * 8); \
    ACC = __builtin_amdgcn_mfma_f32_16x16x32_bf16(hf0, w0, ACC, 0, 0, 0); \
    ACC = __builtin_amdgcn_mfma_f32_16x16x32_bf16(hf1, w1, ACC, 0, 0, 0); }
    L2(0, a20) L2(1, a21) L2(2, a22) L2(3, a23)
#undef L2

#define EPI(CT, ACC) { float bb = b2[(CT) * 16 + c]; \
    _Pragma("unroll") \
    for (int r = 0; r < 4; ++r) { \
        size_t idx = (size_t)(m0 + 4*g + r) * HID + (CT) * 16 + c; \
        float o = ACC[r] + bb; \
        if (last_relu) o = fmaxf(o, 0.f); \
        x_out[idx] = o + x_in[idx]; } }
    EPI(0, a20) EPI(1, a21) EPI(2, a22) EPI(3, a23)
#undef EPI
}

extern "C" void kernel_launch(void* const* d_in, const int* in_sizes, int n_in,
                              void* d_out, int out_size, void* d_ws, size_t ws_size,
                              hipStream_t stream) {
    const float* node_emb = (const float*)d_in[0];
    const float* W1 = (const float*)d_in[1];
    const float* b1 = (const float*)d_in[2];
    const float* W2 = (const float*)d_in[3];
    const float* b2 = (const float*)d_in[4];
    const float* ea = (const float*)d_in[5];
    const int* z = (const int*)d_in[6];
    const int* ei = (const int*)d_in[7];
    const int* src = ei;            // edge_index[0] = message sender
    const int* dst = ei + N_EDGES;  // edge_index[1] = aggregation target

    float* x = (float*)d_out;       // x0 and final output live here
    // workspace (~192 MB): all offsets are 16B-aligned
    unsigned short* eabs = (unsigned short*)d_ws;            // 128 MB bf16 slot-ordered ea
    int* srcs = (int*)(eabs + (size_t)N_EDGES * HID);        // 4 MB
    int2* eid2 = (int2*)(srcs + N_EDGES);                    // 8 MB
    int* offs = (int*)(eid2 + N_EDGES);                      // 0.4 MB
    int* bsum = offs + N_NODES;                              // 128 ints
    float* x1 = (float*)(bsum + 128);                        // 25.6 MB
    float* x2 = x1 + (size_t)N_NODES * HID;                  // 25.6 MB

    const int eb = (N_EDGES + 255) / 256;             // 3907
    const int nodewave_blocks = (N_NODES * 64) / 256; // 25000
    const int conv_blocks = (N_NODES / 16 + 3) / 4;   // 1563 (6250 waves)

    // ---- CSR build (once, reused by all 3 convs) ----
    hipMemsetAsync(offs, 0, N_NODES * sizeof(int), stream);
    prep_kernel<<<GATHER_BLOCKS + HIST_BLOCKS, 256, 0, stream>>>(
        node_emb, z, x, dst, offs);
    scan1_kernel<<<SCAN_NB, SCAN_B, 0, stream>>>(offs, bsum);
    scan2_kernel<<<1, 128, 0, stream>>>(bsum);
    scan3_kernel<<<SCAN_NB, SCAN_B, 0, stream>>>(offs, bsum);
    fill_kernel<<<eb, 256, 0, stream>>>(src, dst, offs, eid2);
    sort_kernel<<<nodewave_blocks, 256, 0, stream>>>(offs, eid2);

    // ---- 3 fused convs, x ping-pong: x -> x1 -> x2 -> x ----
    conv_kernel<1><<<conv_blocks, 256, 0, stream>>>(
        x, x1, ea, eabs, srcs, eid2, offs, W1, b1, W2, b2, 1);
    conv_kernel<0><<<conv_blocks, 256, 0, stream>>>(
        x1, x2, ea, eabs, srcs, eid2, offs,
        W1 + HID * HID, b1 + HID, W2 + HID * HID, b2 + HID, 1);
    conv_kernel<0><<<conv_blocks, 256, 0, stream>>>(
        x2, x, ea, eabs, srcs, eid2, offs,
        W1 + 2 * HID * HID, b1 + 2 * HID, W2 + 2 * HID * HID, b2 + 2 * HID, 0);
}